// Round 2
// baseline (112.440 us; speedup 1.0000x reference)
//
#include <hip/hip_runtime.h>

#define NDOM 8
#define TT   32      // tile dim
#define KDIM 1024    // feature dim (harness-fixed)
#define K0   128     // certificate head dims (bf16 MFMA)
#define RB0  256     // Fb16 row bytes: 128 * 2B
#define RP   272     // LDS row stride bytes: 256 + 16 pad (4-bank skew/row)
#define BMAX 4096    // batch (harness-fixed)
#define GGRID 544    // ~2 tiles/block for T~1100
#define OVF_CAP 8192
#define CERT_T 8.0f  // certificate threshold (quant err bound ~0.7)

typedef float f32x4 __attribute__((ext_vector_type(4)));
typedef short bf16x8 __attribute__((ext_vector_type(8)));

__device__ inline void gload4(const void* g, void* l) {
    __builtin_amdgcn_global_load_lds(
        (const __attribute__((address_space(1))) unsigned int*)g,
        (__attribute__((address_space(3))) unsigned int*)l, 4, 0, 0);
}

__device__ inline unsigned short f2bf(float f) {   // RNE float->bf16
    unsigned u = __float_as_uint(f);
    unsigned r = (u + 0x7fffu + ((u >> 16) & 1u)) >> 16;
    return (unsigned short)r;
}

// ------------------------------------------------------------------ prep ----
// Block 0: label bucketing (ballot/popc) -> perm, dom_off; zeros counters.
// Blocks 1..: 8 rows/block, 2 rows/wave: full sq-norm, tail-norm rb, bf16 head.
__global__ __launch_bounds__(256) void k_prep(
    const float* __restrict__ F, const int* __restrict__ labels, int B,
    unsigned char* __restrict__ Fb16, float* __restrict__ sq,
    float* __restrict__ rb, int* __restrict__ perm, int* __restrict__ dom_off,
    int* __restrict__ ovf_cnt, int* __restrict__ done_cnt) {
    const int t = threadIdx.x, lane = t & 63, wv = t >> 6;

    if (blockIdx.x == 0) {
        __shared__ int lab[BMAX];
        __shared__ unsigned wcnt[4][NDOM];
        if (t == 0) { *ovf_cnt = 0; *done_cnt = 0; }
        for (int i = t; i < BMAX; i += 256) lab[i] = (i < B) ? labels[i] : -1;
        __syncthreads();

        int nch = (B + 63) >> 6;
        int cpw = (nch + 3) >> 2;
        int c0 = wv * cpw, c1 = min(c0 + cpw, nch);
        unsigned long long below = (1ull << lane) - 1ull;

        unsigned cnt[NDOM];
#pragma unroll
        for (int d = 0; d < NDOM; ++d) cnt[d] = 0;
        for (int c = c0; c < c1; ++c) {
            int d = lab[c * 64 + lane];
#pragma unroll
            for (int dd = 0; dd < NDOM; ++dd)
                cnt[dd] += (unsigned)__popcll(__ballot(d == dd));
        }
        if (lane == 0)
#pragma unroll
            for (int dd = 0; dd < NDOM; ++dd) wcnt[wv][dd] = cnt[dd];
        __syncthreads();

        unsigned offs[NDOM + 1];
        offs[0] = 0;
#pragma unroll
        for (int dd = 0; dd < NDOM; ++dd)
            offs[dd + 1] = offs[dd] + wcnt[0][dd] + wcnt[1][dd] + wcnt[2][dd] + wcnt[3][dd];
        if (t <= NDOM) dom_off[t] = (int)offs[t];

        unsigned run[NDOM];
#pragma unroll
        for (int dd = 0; dd < NDOM; ++dd) {
            unsigned base = offs[dd];
            for (int w = 0; w < 4; ++w)
                if (w < wv) base += wcnt[w][dd];
            run[dd] = base;
        }
        for (int c = c0; c < c1; ++c) {
            int i = c * 64 + lane;
            int d = lab[i];
            int pos = -1;
#pragma unroll
            for (int dd = 0; dd < NDOM; ++dd) {
                unsigned long long m = __ballot(d == dd);
                if (d == dd) pos = (int)run[dd] + __popcll(m & below);
                run[dd] += (unsigned)__popcll(m);
            }
            if (i < B) perm[pos] = i;
        }
        return;
    }

    int base = (int)(blockIdx.x - 1) * 8 + wv * 2;
#pragma unroll
    for (int rr = 0; rr < 2; ++rr) {
        int row = base + rr;
        if (row >= B) continue;
        const float4* srow = (const float4*)(F + (size_t)row * KDIM);
        float ss = 0.f, s0 = 0.f;
#pragma unroll
        for (int it = 0; it < 4; ++it) {
            float4 v = srow[it * 64 + lane];
            float d = v.x * v.x + v.y * v.y + v.z * v.z + v.w * v.w;
            ss += d;
            if (it == 0 && lane < 32) {            // head dims 0..127
                s0 = d;
                ushort4 p;
                p.x = f2bf(v.x); p.y = f2bf(v.y); p.z = f2bf(v.z); p.w = f2bf(v.w);
                ((ushort4*)(Fb16 + (size_t)row * RB0))[lane] = p;
            }
        }
#pragma unroll
        for (int s = 32; s > 0; s >>= 1) {
            ss += __shfl_xor(ss, s);
            s0 += __shfl_xor(s0, s);
        }
        if (lane == 0) {
            sq[row] = ss;
            rb[row] = sqrtf(fmaxf(ss - s0, 0.f));
        }
    }
}

// ------------------------------------------------------------------ gram ----
// Certificate pass + fused finalize (last-done block). cert = sa+sb-2*a0.b0
// - 2*rb_a*rb_b  (== |a0-b0|^2 + (rb_a-rb_b)^2 >= true d2). cert > T proves
// relu(1-dist) == 0 exactly. Failures -> overflow list (exact fp32 fixup).
__global__ __launch_bounds__(256) void k_gram(
    const float* __restrict__ F, const unsigned char* __restrict__ Fb16,
    const float* __restrict__ sq, const float* __restrict__ rb,
    const int* __restrict__ perm, const int* __restrict__ dom_off,
    int* __restrict__ ovf_cnt, int4* __restrict__ ovf,
    int* __restrict__ done_cnt, float* __restrict__ out) {
    __shared__ __align__(16) unsigned char lA[TT * RP];   // 8.5 KB
    __shared__ __align__(16) unsigned char lB[TT * RP];   // 8.5 KB
    __shared__ int s_p[64];
    __shared__ float s_sq[64], s_rb[64];
    __shared__ int s_offs[NDOM + 1], s_ts[NDOM + 1];

    const int t = threadIdx.x, lane = t & 63, wv = t >> 6;
    const int m16 = lane & 15, quad = lane >> 4;
    const int wm = (wv & 1) * 16, wn = (wv >> 1) * 16;

    if (t == 0) {
        int T = 0;
        for (int d = 0; d < NDOM; ++d) {
            int o0 = dom_off[d], o1 = dom_off[d + 1];
            s_offs[d] = o0;
            s_ts[d] = T;
            int n = o1 - o0;
            int nt = (n + TT - 1) / TT;
            T += nt * (nt + 1) / 2;
        }
        s_offs[NDOM] = dom_off[NDOM];
        s_ts[NDOM] = T;
    }
    __syncthreads();
    const int T = s_ts[NDOM];

    for (int tile = blockIdx.x; tile < T; tile += gridDim.x) {
        int dom = 0;
        while (tile >= s_ts[dom + 1]) ++dom;
        int off = s_offs[dom], n = s_offs[dom + 1] - off;
        int nt = (n + TT - 1) / TT;
        int rel = tile - s_ts[dom];
        int ty = 0, rem = rel;
        while (rem >= nt - ty) { rem -= nt - ty; ++ty; }
        int tx = ty + rem;
        int tr = ty * TT, tc = tx * TT;
        bool diag = (ty == tx);

        if (t < 64) {
            int r = (t < 32) ? min(tr + t, n - 1) : min(tc + (t - 32), n - 1);
            int p = perm[off + r];
            s_p[t] = p;
            s_sq[t] = sq[p];
            s_rb[t] = rb[p];
        }
        __syncthreads();

        // stage: one 256B row per gload4 call (rows gathered via perm)
#pragma unroll
        for (int j = 0; j < 16; ++j) {
            int r = wv * 16 + j;          // 0..63: A rows 0..31, B rows 32..63
            if (r < 32) {
                const unsigned char* g = Fb16 + (size_t)s_p[r] * RB0 + lane * 4;
                gload4(g, lA + r * RP);
            } else if (!diag) {
                const unsigned char* g = Fb16 + (size_t)s_p[r] * RB0 + lane * 4;
                gload4(g, lB + (r - 32) * RP);
            }
        }
        __syncthreads();   // single vmcnt drain per tile

        const unsigned char* Bbuf = diag ? lA : lB;
        const unsigned char* pa = lA + (wm + m16) * RP + quad * 16;
        const unsigned char* pb = Bbuf + (wn + m16) * RP + quad * 16;
        f32x4 ac = (f32x4){0.f, 0.f, 0.f, 0.f};
#pragma unroll
        for (int ks = 0; ks < 4; ++ks) {    // K0=128 = 4 x K32 MFMA
            bf16x8 a = *(const bf16x8*)(pa + ks * 64);
            bf16x8 b = *(const bf16x8*)(pb + ks * 64);
            ac = __builtin_amdgcn_mfma_f32_16x16x32_bf16(a, b, ac, 0, 0, 0);
        }

        int lr0 = wm + quad * 4;
        int lc = wn + m16;
        int pc = tc + lc;
        if (pc < n) {
            float sb = s_sq[32 + lc], rbb = s_rb[32 + lc];
#pragma unroll
            for (int r = 0; r < 4; ++r) {
                int pr = tr + lr0 + r;
                if (pr < n && pr != pc) {
                    float cert = s_sq[lr0 + r] + sb
                               - 2.0f * ac[r] - 2.0f * s_rb[lr0 + r] * rbb;
                    if (cert <= CERT_T) {         // can't certify zero -> exact path
                        int slot = atomicAdd(ovf_cnt, 1);
                        if (slot < OVF_CAP) {
                            int4 rec;
                            rec.x = s_p[lr0 + r];
                            rec.y = s_p[32 + lc];
                            rec.z = diag ? 1 : 2;  // pair multiplicity
                            rec.w = dom;
                            ovf[slot] = rec;
                        }
                    }
                }
            }
        }
        __syncthreads();   // LDS reuse fence before next tile
    }

    // ---------------- fused finalize: last block to finish does it ----------
    __threadfence();                       // publish ovf writes device-wide
    __shared__ int s_last;
    if (t == 0)
        s_last = (atomicAdd(done_cnt, 1) == (int)gridDim.x - 1) ? 1 : 0;
    __syncthreads();
    if (!s_last) return;
    __threadfence();                       // acquire: see all blocks' ovf

    __shared__ float dsum[NDOM];
    if (t < NDOM) dsum[t] = 0.f;
    __syncthreads();

    int cnt = atomicAdd(ovf_cnt, 0);
    if (cnt > OVF_CAP) cnt = OVF_CAP;
    for (int e = wv; e < cnt; e += 4) {    // one wave per overflow pair
        int4 rec = ovf[e];
        const float4* ra = (const float4*)(F + (size_t)rec.x * KDIM);
        const float4* rbp = (const float4*)(F + (size_t)rec.y * KDIM);
        float dot = 0.f;
#pragma unroll
        for (int it = 0; it < 4; ++it) {
            float4 va = ra[it * 64 + lane], vb = rbp[it * 64 + lane];
            dot += va.x * vb.x + va.y * vb.y + va.z * vb.z + va.w * vb.w;
        }
#pragma unroll
        for (int s = 32; s > 0; s >>= 1) dot += __shfl_xor(dot, s);
        if (lane == 0) {
            float d2 = fmaxf(sq[rec.x] + sq[rec.y] - 2.f * dot, 0.f);
            float val = fmaxf(1.f - sqrtf(d2), 0.f) * (float)rec.z;
            atomicAdd(&dsum[rec.w], val);
        }
    }
    __syncthreads();
    if (t == 0) {
        float acc = 0.f;
        int v = 0;
        for (int d = 0; d < NDOM; ++d) {
            int n = dom_off[d + 1] - dom_off[d];
            if (n > 1) {
                acc += ((float)n + dsum[d]) / ((float)n * (float)n);
                ++v;
            }
        }
        out[0] = (v > 0) ? acc / (float)v : 0.f;
    }
}

// ---------------------------------------------------------------- launch ----
extern "C" void kernel_launch(void* const* d_in, const int* in_sizes, int n_in,
                              void* d_out, int out_size, void* d_ws, size_t ws_size,
                              hipStream_t stream) {
    const float* F = (const float*)d_in[0];
    const int* labels = (const int*)d_in[1];
    int B = in_sizes[1];                 // 4096

    char* ws = (char*)d_ws;
    size_t o = 0;
    unsigned char* Fb16 = (unsigned char*)(ws + o); o += (size_t)BMAX * RB0;  // 1 MB
    float* sq = (float*)(ws + o);      o += (size_t)BMAX * 4;
    float* rb = (float*)(ws + o);      o += (size_t)BMAX * 4;
    int* perm = (int*)(ws + o);        o += (size_t)BMAX * 4;
    int* dom_off = (int*)(ws + o);     o += 64;
    int* ovf_cnt = (int*)(ws + o);     o += 64;
    int* done_cnt = (int*)(ws + o);    o += 64;
    int4* ovf = (int4*)(ws + o);       o += (size_t)OVF_CAP * 16;

    int nconv = (B + 7) >> 3;
    k_prep<<<nconv + 1, 256, 0, stream>>>(F, labels, B, Fb16, sq, rb, perm,
                                          dom_off, ovf_cnt, done_cnt);
    k_gram<<<GGRID, 256, 0, stream>>>(F, Fb16, sq, rb, perm, dom_off,
                                      ovf_cnt, ovf, done_cnt, (float*)d_out);
}

// Round 3
// 85.698 us; speedup vs baseline: 1.3120x; 1.3120x over previous
//
#include <hip/hip_runtime.h>

#define NDOM 8
#define TT   32      // tile dim
#define KDIM 1024    // feature dim (harness-fixed)
#define K0   128     // certificate head dims (bf16 MFMA)
#define RB0  256     // Fb16 row bytes: 128 * 2B
#define RP   272     // LDS row stride bytes: 256 + 16 pad (4-bank skew/row)
#define BMAX 4096    // batch (harness-fixed)
#define GGRID 544    // ~2 tiles/block for T~1100
#define OVF_CAP 8192
#define CERT_T 8.0f  // certificate threshold (quant err bound ~0.7)

typedef float f32x4 __attribute__((ext_vector_type(4)));
typedef short bf16x8 __attribute__((ext_vector_type(8)));

__device__ inline void gload4(const void* g, void* l) {
    __builtin_amdgcn_global_load_lds(
        (const __attribute__((address_space(1))) unsigned int*)g,
        (__attribute__((address_space(3))) unsigned int*)l, 4, 0, 0);
}

__device__ inline unsigned short f2bf(float f) {   // RNE float->bf16
    unsigned u = __float_as_uint(f);
    unsigned r = (u + 0x7fffu + ((u >> 16) & 1u)) >> 16;
    return (unsigned short)r;
}

// Coherent-point atomics (sc1: bypass non-coherent per-XCD L2; NO cache
// writeback/invalidate, unlike __threadfence which wbl2+invl2's the XCD).
__device__ inline int agent_add(int* p, int v) {
    return __hip_atomic_fetch_add(p, v, __ATOMIC_RELAXED, __HIP_MEMORY_SCOPE_AGENT);
}
__device__ inline int agent_ld(const int* p) {
    return __hip_atomic_load(p, __ATOMIC_RELAXED, __HIP_MEMORY_SCOPE_AGENT);
}
__device__ inline void agent_st(int* p, int v) {
    __hip_atomic_store(p, v, __ATOMIC_RELAXED, __HIP_MEMORY_SCOPE_AGENT);
}

// ------------------------------------------------------------------ prep ----
// Block 0: label bucketing (ballot/popc) -> perm, dom_off; zeros counters.
// Blocks 1..: 8 rows/block, 2 rows/wave: full sq-norm, tail-norm rb, bf16 head.
__global__ __launch_bounds__(256) void k_prep(
    const float* __restrict__ F, const int* __restrict__ labels, int B,
    unsigned char* __restrict__ Fb16, float* __restrict__ sq,
    float* __restrict__ rb, int* __restrict__ perm, int* __restrict__ dom_off,
    int* __restrict__ ctrs) {           // ctrs[0]=ovf_res ctrs[1]=ovf_com ctrs[2]=done
    const int t = threadIdx.x, lane = t & 63, wv = t >> 6;

    if (blockIdx.x == 0) {
        __shared__ int lab[BMAX];
        __shared__ unsigned wcnt[4][NDOM];
        if (t < 3) ctrs[t] = 0;
        for (int i = t; i < BMAX; i += 256) lab[i] = (i < B) ? labels[i] : -1;
        __syncthreads();

        int nch = (B + 63) >> 6;
        int cpw = (nch + 3) >> 2;
        int c0 = wv * cpw, c1 = min(c0 + cpw, nch);
        unsigned long long below = (1ull << lane) - 1ull;

        unsigned cnt[NDOM];
#pragma unroll
        for (int d = 0; d < NDOM; ++d) cnt[d] = 0;
        for (int c = c0; c < c1; ++c) {
            int d = lab[c * 64 + lane];
#pragma unroll
            for (int dd = 0; dd < NDOM; ++dd)
                cnt[dd] += (unsigned)__popcll(__ballot(d == dd));
        }
        if (lane == 0)
#pragma unroll
            for (int dd = 0; dd < NDOM; ++dd) wcnt[wv][dd] = cnt[dd];
        __syncthreads();

        unsigned offs[NDOM + 1];
        offs[0] = 0;
#pragma unroll
        for (int dd = 0; dd < NDOM; ++dd)
            offs[dd + 1] = offs[dd] + wcnt[0][dd] + wcnt[1][dd] + wcnt[2][dd] + wcnt[3][dd];
        if (t <= NDOM) dom_off[t] = (int)offs[t];

        unsigned run[NDOM];
#pragma unroll
        for (int dd = 0; dd < NDOM; ++dd) {
            unsigned base = offs[dd];
            for (int w = 0; w < 4; ++w)
                if (w < wv) base += wcnt[w][dd];
            run[dd] = base;
        }
        for (int c = c0; c < c1; ++c) {
            int i = c * 64 + lane;
            int d = lab[i];
            int pos = -1;
#pragma unroll
            for (int dd = 0; dd < NDOM; ++dd) {
                unsigned long long m = __ballot(d == dd);
                if (d == dd) pos = (int)run[dd] + __popcll(m & below);
                run[dd] += (unsigned)__popcll(m);
            }
            if (i < B) perm[pos] = i;
        }
        return;
    }

    int base = (int)(blockIdx.x - 1) * 8 + wv * 2;
#pragma unroll
    for (int rr = 0; rr < 2; ++rr) {
        int row = base + rr;
        if (row >= B) continue;
        const float4* srow = (const float4*)(F + (size_t)row * KDIM);
        float ss = 0.f, s0 = 0.f;
#pragma unroll
        for (int it = 0; it < 4; ++it) {
            float4 v = srow[it * 64 + lane];
            float d = v.x * v.x + v.y * v.y + v.z * v.z + v.w * v.w;
            ss += d;
            if (it == 0 && lane < 32) {            // head dims 0..127
                s0 = d;
                ushort4 p;
                p.x = f2bf(v.x); p.y = f2bf(v.y); p.z = f2bf(v.z); p.w = f2bf(v.w);
                ((ushort4*)(Fb16 + (size_t)row * RB0))[lane] = p;
            }
        }
#pragma unroll
        for (int s = 32; s > 0; s >>= 1) {
            ss += __shfl_xor(ss, s);
            s0 += __shfl_xor(s0, s);
        }
        if (lane == 0) {
            sq[row] = ss;
            rb[row] = sqrtf(fmaxf(ss - s0, 0.f));
        }
    }
}

// ------------------------------------------------------------------ gram ----
// Certificate pass + fused finalize (last-done block, fence-free protocol).
// cert = sa+sb-2*a0.b0-2*rb_a*rb_b (== |a0-b0|^2+(rb_a-rb_b)^2 >= true d2).
// cert > T proves relu(1-dist)==0 exactly. Failures -> overflow list via
// coherent-point atomics; exact fp32 fixup by the elected last block.
__global__ __launch_bounds__(256) void k_gram(
    const float* __restrict__ F, const unsigned char* __restrict__ Fb16,
    const float* __restrict__ sq, const float* __restrict__ rb,
    const int* __restrict__ perm, const int* __restrict__ dom_off,
    int* __restrict__ ctrs, int* __restrict__ ovf, float* __restrict__ out) {
    __shared__ __align__(16) unsigned char lA[TT * RP];   // 8.5 KB
    __shared__ __align__(16) unsigned char lB[TT * RP];   // 8.5 KB
    __shared__ int s_p[64];
    __shared__ float s_sq[64], s_rb[64];
    __shared__ int s_offs[NDOM + 1], s_ts[NDOM + 1];

    int* ovf_res = ctrs + 0;
    int* ovf_com = ctrs + 1;
    int* done_cnt = ctrs + 2;

    const int t = threadIdx.x, lane = t & 63, wv = t >> 6;
    const int m16 = lane & 15, quad = lane >> 4;
    const int wm = (wv & 1) * 16, wn = (wv >> 1) * 16;

    if (t == 0) {
        int T = 0;
        for (int d = 0; d < NDOM; ++d) {
            int o0 = dom_off[d], o1 = dom_off[d + 1];
            s_offs[d] = o0;
            s_ts[d] = T;
            int n = o1 - o0;
            int nt = (n + TT - 1) / TT;
            T += nt * (nt + 1) / 2;
        }
        s_offs[NDOM] = dom_off[NDOM];
        s_ts[NDOM] = T;
    }
    __syncthreads();
    const int T = s_ts[NDOM];

    for (int tile = blockIdx.x; tile < T; tile += gridDim.x) {
        int dom = 0;
        while (tile >= s_ts[dom + 1]) ++dom;
        int off = s_offs[dom], n = s_offs[dom + 1] - off;
        int nt = (n + TT - 1) / TT;
        int rel = tile - s_ts[dom];
        int ty = 0, rem = rel;
        while (rem >= nt - ty) { rem -= nt - ty; ++ty; }
        int tx = ty + rem;
        int tr = ty * TT, tc = tx * TT;
        bool diag = (ty == tx);

        if (t < 64) {
            int r = (t < 32) ? min(tr + t, n - 1) : min(tc + (t - 32), n - 1);
            int p = perm[off + r];
            s_p[t] = p;
            s_sq[t] = sq[p];
            s_rb[t] = rb[p];
        }
        __syncthreads();

        // stage: one 256B row per gload4 call (rows gathered via perm)
#pragma unroll
        for (int j = 0; j < 16; ++j) {
            int r = wv * 16 + j;          // 0..63: A rows 0..31, B rows 32..63
            if (r < 32) {
                const unsigned char* g = Fb16 + (size_t)s_p[r] * RB0 + lane * 4;
                gload4(g, lA + r * RP);
            } else if (!diag) {
                const unsigned char* g = Fb16 + (size_t)s_p[r] * RB0 + lane * 4;
                gload4(g, lB + (r - 32) * RP);
            }
        }
        __syncthreads();   // single vmcnt drain per tile

        const unsigned char* Bbuf = diag ? lA : lB;
        const unsigned char* pa = lA + (wm + m16) * RP + quad * 16;
        const unsigned char* pb = Bbuf + (wn + m16) * RP + quad * 16;
        f32x4 ac = (f32x4){0.f, 0.f, 0.f, 0.f};
#pragma unroll
        for (int ks = 0; ks < 4; ++ks) {    // K0=128 = 4 x K32 MFMA
            bf16x8 a = *(const bf16x8*)(pa + ks * 64);
            bf16x8 b = *(const bf16x8*)(pb + ks * 64);
            ac = __builtin_amdgcn_mfma_f32_16x16x32_bf16(a, b, ac, 0, 0, 0);
        }

        int lr0 = wm + quad * 4;
        int lc = wn + m16;
        int pc = tc + lc;
        if (pc < n) {
            float sb = s_sq[32 + lc], rbb = s_rb[32 + lc];
#pragma unroll
            for (int r = 0; r < 4; ++r) {
                int pr = tr + lr0 + r;
                if (pr < n && pr != pc) {
                    float cert = s_sq[lr0 + r] + sb
                               - 2.0f * ac[r] - 2.0f * s_rb[lr0 + r] * rbb;
                    if (cert <= CERT_T) {         // can't certify zero -> exact path
                        int slot = agent_add(ovf_res, 1);
                        if (slot < OVF_CAP) {
                            int* rp = ovf + slot * 4;
                            agent_st(rp + 0, s_p[lr0 + r]);
                            agent_st(rp + 1, s_p[32 + lc]);
                            agent_st(rp + 2, diag ? 1 : 2);  // multiplicity
                            agent_st(rp + 3, dom);
                            // drain record stores to coherent point, then commit
                            asm volatile("s_waitcnt vmcnt(0)" ::: "memory");
                            agent_add(ovf_com, 1);
                        }
                    }
                }
            }
        }
        __syncthreads();   // LDS reuse fence before next tile
    }

    // ------------- fused finalize: fence-free last-done-block election ------
    // Every wave drains its own vmem (res/com increments reach the coherent
    // point) BEFORE the block's done++ -> when the last block is elected, all
    // counters/records device-wide are final. No cache wb/inv anywhere.
    asm volatile("s_waitcnt vmcnt(0)" ::: "memory");
    __syncthreads();
    __shared__ int s_last;
    if (t == 0)
        s_last = (agent_add(done_cnt, 1) == (int)gridDim.x - 1) ? 1 : 0;
    __syncthreads();
    if (!s_last) return;

    int res = agent_ld(ovf_res);
    int want = (res > OVF_CAP) ? OVF_CAP : res;
    // bounded defensive spin (expected: zero iterations)
    for (int it = 0; it < (1 << 20) && agent_ld(ovf_com) < want; ++it)
        __builtin_amdgcn_s_sleep(1);

    __shared__ float dsum[NDOM];
    if (t < NDOM) dsum[t] = 0.f;
    __syncthreads();

    for (int e = wv; e < want; e += 4) {    // one wave per overflow pair
        const int* rp = ovf + e * 4;
        int ra_i = agent_ld(rp + 0);
        int rb_i = agent_ld(rp + 1);
        int mult = agent_ld(rp + 2);
        int domd = agent_ld(rp + 3);
        const float4* ra = (const float4*)(F + (size_t)ra_i * KDIM);
        const float4* rbp = (const float4*)(F + (size_t)rb_i * KDIM);
        float dot = 0.f;
#pragma unroll
        for (int it = 0; it < 4; ++it) {
            float4 va = ra[it * 64 + lane], vb = rbp[it * 64 + lane];
            dot += va.x * vb.x + va.y * vb.y + va.z * vb.z + va.w * vb.w;
        }
#pragma unroll
        for (int s = 32; s > 0; s >>= 1) dot += __shfl_xor(dot, s);
        if (lane == 0) {
            float d2 = fmaxf(sq[ra_i] + sq[rb_i] - 2.f * dot, 0.f);
            float val = fmaxf(1.f - sqrtf(d2), 0.f) * (float)mult;
            atomicAdd(&dsum[domd], val);
        }
    }
    __syncthreads();
    if (t == 0) {
        float acc = 0.f;
        int v = 0;
        for (int d = 0; d < NDOM; ++d) {
            int n = dom_off[d + 1] - dom_off[d];
            if (n > 1) {
                acc += ((float)n + dsum[d]) / ((float)n * (float)n);
                ++v;
            }
        }
        out[0] = (v > 0) ? acc / (float)v : 0.f;
    }
}

// ---------------------------------------------------------------- launch ----
extern "C" void kernel_launch(void* const* d_in, const int* in_sizes, int n_in,
                              void* d_out, int out_size, void* d_ws, size_t ws_size,
                              hipStream_t stream) {
    const float* F = (const float*)d_in[0];
    const int* labels = (const int*)d_in[1];
    int B = in_sizes[1];                 // 4096

    char* ws = (char*)d_ws;
    size_t o = 0;
    unsigned char* Fb16 = (unsigned char*)(ws + o); o += (size_t)BMAX * RB0;  // 1 MB
    float* sq = (float*)(ws + o);      o += (size_t)BMAX * 4;
    float* rb = (float*)(ws + o);      o += (size_t)BMAX * 4;
    int* perm = (int*)(ws + o);        o += (size_t)BMAX * 4;
    int* dom_off = (int*)(ws + o);     o += 64;
    int* ctrs = (int*)(ws + o);        o += 64;   // [res, com, done]
    int* ovf = (int*)(ws + o);         o += (size_t)OVF_CAP * 16;

    int nconv = (B + 7) >> 3;
    k_prep<<<nconv + 1, 256, 0, stream>>>(F, labels, B, Fb16, sq, rb, perm,
                                          dom_off, ctrs);
    k_gram<<<GGRID, 256, 0, stream>>>(F, Fb16, sq, rb, perm, dom_off,
                                      ctrs, ovf, (float*)d_out);
}

// Round 4
// 83.185 us; speedup vs baseline: 1.3517x; 1.0302x over previous
//
#include <hip/hip_runtime.h>

#define NDOM 8
#define TT   32      // tile dim
#define KDIM 1024    // feature dim (harness-fixed)
#define K0   128     // certificate head dims (bf16 MFMA)
#define RB0  256     // Fb16 row bytes: 128 * 2B
#define RP   272     // LDS row stride bytes: 256 + 16 pad (4-bank skew/row)
#define BMAX 4096    // batch (harness-fixed)
#define GGRID 512
#define OVF_CAP 8192
#define CERT_T 8.0f  // certificate threshold (quant err bound ~0.7)

typedef float f32x4 __attribute__((ext_vector_type(4)));
typedef short bf16x8 __attribute__((ext_vector_type(8)));

__device__ inline void gload4(const void* g, void* l) {
    __builtin_amdgcn_global_load_lds(
        (const __attribute__((address_space(1))) unsigned int*)g,
        (__attribute__((address_space(3))) unsigned int*)l, 4, 0, 0);
}

__device__ inline unsigned short f2bf(float f) {   // RNE float->bf16
    unsigned u = __float_as_uint(f);
    unsigned r = (u + 0x7fffu + ((u >> 16) & 1u)) >> 16;
    return (unsigned short)r;
}

// ------------------------------------------------------------------ prep ----
// Block 0: label bucketing (ballot/popc) -> perm, dom_off; zeros ovf_cnt.
// Blocks 1..: per row (1 row/wave): full sq-norm, tail-norm rb, bf16 head.
__global__ __launch_bounds__(256) void k_prep(
    const float* __restrict__ F, const int* __restrict__ labels, int B,
    unsigned char* __restrict__ Fb16, float* __restrict__ sq,
    float* __restrict__ rb, int* __restrict__ perm, int* __restrict__ dom_off,
    int* __restrict__ ovf_cnt) {
    const int t = threadIdx.x, lane = t & 63, wv = t >> 6;

    if (blockIdx.x == 0) {
        __shared__ int lab[BMAX];
        __shared__ unsigned wcnt[4][NDOM];
        if (t == 0) *ovf_cnt = 0;
        for (int i = t; i < BMAX; i += 256) lab[i] = (i < B) ? labels[i] : -1;
        __syncthreads();

        int nch = (B + 63) >> 6;
        int cpw = (nch + 3) >> 2;
        int c0 = wv * cpw, c1 = min(c0 + cpw, nch);
        unsigned long long below = (1ull << lane) - 1ull;

        unsigned cnt[NDOM];
#pragma unroll
        for (int d = 0; d < NDOM; ++d) cnt[d] = 0;
        for (int c = c0; c < c1; ++c) {
            int d = lab[c * 64 + lane];
#pragma unroll
            for (int dd = 0; dd < NDOM; ++dd)
                cnt[dd] += (unsigned)__popcll(__ballot(d == dd));
        }
        if (lane == 0)
#pragma unroll
            for (int dd = 0; dd < NDOM; ++dd) wcnt[wv][dd] = cnt[dd];
        __syncthreads();

        unsigned offs[NDOM + 1];
        offs[0] = 0;
#pragma unroll
        for (int dd = 0; dd < NDOM; ++dd)
            offs[dd + 1] = offs[dd] + wcnt[0][dd] + wcnt[1][dd] + wcnt[2][dd] + wcnt[3][dd];
        if (t <= NDOM) dom_off[t] = (int)offs[t];

        unsigned run[NDOM];
#pragma unroll
        for (int dd = 0; dd < NDOM; ++dd) {
            unsigned base = offs[dd];
            for (int w = 0; w < 4; ++w)
                if (w < wv) base += wcnt[w][dd];
            run[dd] = base;
        }
        for (int c = c0; c < c1; ++c) {
            int i = c * 64 + lane;
            int d = lab[i];
            int pos = -1;
#pragma unroll
            for (int dd = 0; dd < NDOM; ++dd) {
                unsigned long long m = __ballot(d == dd);
                if (d == dd) pos = (int)run[dd] + __popcll(m & below);
                run[dd] += (unsigned)__popcll(m);
            }
            if (i < B) perm[pos] = i;
        }
        return;
    }

    int row = (int)(blockIdx.x - 1) * 4 + wv;
    if (row >= B) return;
    const float4* srow = (const float4*)(F + (size_t)row * KDIM);
    float ss = 0.f, s0 = 0.f;
#pragma unroll
    for (int it = 0; it < 4; ++it) {
        float4 v = srow[it * 64 + lane];
        float d = v.x * v.x + v.y * v.y + v.z * v.z + v.w * v.w;
        ss += d;
        if (it == 0 && lane < 32) {            // head dims 0..127
            s0 = d;
            ushort4 p;
            p.x = f2bf(v.x); p.y = f2bf(v.y); p.z = f2bf(v.z); p.w = f2bf(v.w);
            ((ushort4*)(Fb16 + (size_t)row * RB0))[lane] = p;
        }
    }
#pragma unroll
    for (int s = 32; s > 0; s >>= 1) {
        ss += __shfl_xor(ss, s);
        s0 += __shfl_xor(s0, s);
    }
    if (lane == 0) {
        sq[row] = ss;
        rb[row] = sqrtf(fmaxf(ss - s0, 0.f));
    }
}

// ------------------------------------------------------------------ gram ----
// Certificate pass: per off-diag intra-domain pair, cert = sa+sb-2*a0.b0
// - 2*rb_a*rb_b  (== |a0-b0|^2 + (rb_a-rb_b)^2 >= true d2). cert > T proves
// relu(1-dist) == 0 exactly. Failures -> overflow list (exact fixup in final).
__global__ __launch_bounds__(256) void k_gram(
    const unsigned char* __restrict__ Fb16, const float* __restrict__ sq,
    const float* __restrict__ rb, const int* __restrict__ perm,
    const int* __restrict__ dom_off, int* __restrict__ ovf_cnt,
    int4* __restrict__ ovf) {
    __shared__ __align__(16) unsigned char lA[TT * RP];   // 8.5 KB
    __shared__ __align__(16) unsigned char lB[TT * RP];   // 8.5 KB
    __shared__ int s_p[64];
    __shared__ float s_sq[64], s_rb[64];
    __shared__ int s_offs[NDOM + 1], s_ts[NDOM + 1];

    const int t = threadIdx.x, lane = t & 63, wv = t >> 6;
    const int m16 = lane & 15, quad = lane >> 4;
    const int wm = (wv & 1) * 16, wn = (wv >> 1) * 16;

    if (t == 0) {
        int T = 0;
        for (int d = 0; d < NDOM; ++d) {
            int o0 = dom_off[d], o1 = dom_off[d + 1];
            s_offs[d] = o0;
            s_ts[d] = T;
            int n = o1 - o0;
            int nt = (n + TT - 1) / TT;
            T += nt * (nt + 1) / 2;
        }
        s_offs[NDOM] = dom_off[NDOM];
        s_ts[NDOM] = T;
    }
    __syncthreads();
    const int T = s_ts[NDOM];

    for (int tile = blockIdx.x; tile < T; tile += gridDim.x) {
        int dom = 0;
        while (tile >= s_ts[dom + 1]) ++dom;
        int off = s_offs[dom], n = s_offs[dom + 1] - off;
        int nt = (n + TT - 1) / TT;
        int rel = tile - s_ts[dom];
        int ty = 0, rem = rel;
        while (rem >= nt - ty) { rem -= nt - ty; ++ty; }
        int tx = ty + rem;
        int tr = ty * TT, tc = tx * TT;
        bool diag = (ty == tx);

        if (t < 64) {
            int r = (t < 32) ? min(tr + t, n - 1) : min(tc + (t - 32), n - 1);
            int p = perm[off + r];
            s_p[t] = p;
            s_sq[t] = sq[p];
            s_rb[t] = rb[p];
        }
        __syncthreads();

        // stage: one 256B row per gload4 call (rows gathered via perm)
#pragma unroll
        for (int j = 0; j < 16; ++j) {
            int r = wv * 16 + j;          // 0..63: A rows 0..31, B rows 32..63
            if (r < 32) {
                const unsigned char* g = Fb16 + (size_t)s_p[r] * RB0 + lane * 4;
                gload4(g, lA + r * RP);
            } else if (!diag) {
                const unsigned char* g = Fb16 + (size_t)s_p[r] * RB0 + lane * 4;
                gload4(g, lB + (r - 32) * RP);
            }
        }
        __syncthreads();   // single vmcnt drain per tile

        const unsigned char* Bbuf = diag ? lA : lB;
        const unsigned char* pa = lA + (wm + m16) * RP + quad * 16;
        const unsigned char* pb = Bbuf + (wn + m16) * RP + quad * 16;
        f32x4 ac = (f32x4){0.f, 0.f, 0.f, 0.f};
#pragma unroll
        for (int ks = 0; ks < 4; ++ks) {    // K0=128 = 4 x K32 MFMA
            bf16x8 a = *(const bf16x8*)(pa + ks * 64);
            bf16x8 b = *(const bf16x8*)(pb + ks * 64);
            ac = __builtin_amdgcn_mfma_f32_16x16x32_bf16(a, b, ac, 0, 0, 0);
        }

        int lr0 = wm + quad * 4;
        int lc = wn + m16;
        int pc = tc + lc;
        if (pc < n) {
            float sb = s_sq[32 + lc], rbb = s_rb[32 + lc];
#pragma unroll
            for (int r = 0; r < 4; ++r) {
                int pr = tr + lr0 + r;
                if (pr < n && pr != pc) {
                    float cert = s_sq[lr0 + r] + sb
                               - 2.0f * ac[r] - 2.0f * s_rb[lr0 + r] * rbb;
                    if (cert <= CERT_T) {         // can't certify zero -> exact path
                        int slot = atomicAdd(ovf_cnt, 1);
                        if (slot < OVF_CAP) {
                            int4 rec;
                            rec.x = s_p[lr0 + r];
                            rec.y = s_p[32 + lc];
                            rec.z = diag ? 1 : 2;  // pair multiplicity
                            rec.w = dom;
                            ovf[slot] = rec;
                        }
                    }
                }
            }
        }
        __syncthreads();   // LDS reuse fence before next tile
    }
}

// -------------------------------------------------------------- finalize ----
// per_domain = (n_d  [diag, exact]  + overflow fixups) / n_d^2 ; mean over n>1.
__global__ __launch_bounds__(256) void k_final(
    const float* __restrict__ F, const float* __restrict__ sq,
    const int* __restrict__ dom_off, const int* __restrict__ ovf_cnt,
    const int4* __restrict__ ovf, float* __restrict__ out) {
    __shared__ float dsum[NDOM];
    const int t = threadIdx.x, lane = t & 63, wv = t >> 6;
    if (t < NDOM) dsum[t] = 0.f;
    __syncthreads();

    int cnt = *ovf_cnt;
    if (cnt > OVF_CAP) cnt = OVF_CAP;
    for (int e = wv; e < cnt; e += 4) {       // one wave per overflow pair
        int4 rec = ovf[e];
        const float4* ra = (const float4*)(F + (size_t)rec.x * KDIM);
        const float4* rbp = (const float4*)(F + (size_t)rec.y * KDIM);
        float dot = 0.f;
#pragma unroll
        for (int it = 0; it < 4; ++it) {
            float4 va = ra[it * 64 + lane], vb = rbp[it * 64 + lane];
            dot += va.x * vb.x + va.y * vb.y + va.z * vb.z + va.w * vb.w;
        }
#pragma unroll
        for (int s = 32; s > 0; s >>= 1) dot += __shfl_xor(dot, s);
        if (lane == 0) {
            float d2 = fmaxf(sq[rec.x] + sq[rec.y] - 2.f * dot, 0.f);
            float val = fmaxf(1.f - sqrtf(d2), 0.f) * (float)rec.z;
            atomicAdd(&dsum[rec.w], val);
        }
    }
    __syncthreads();
    if (t == 0) {
        float acc = 0.f;
        int v = 0;
        for (int dd = 0; dd < NDOM; ++dd) {
            int n = dom_off[dd + 1] - dom_off[dd];
            if (n > 1) {
                acc += ((float)n + dsum[dd]) / ((float)n * (float)n);
                ++v;
            }
        }
        out[0] = (v > 0) ? acc / (float)v : 0.f;
    }
}

// ---------------------------------------------------------------- launch ----
extern "C" void kernel_launch(void* const* d_in, const int* in_sizes, int n_in,
                              void* d_out, int out_size, void* d_ws, size_t ws_size,
                              hipStream_t stream) {
    const float* F = (const float*)d_in[0];
    const int* labels = (const int*)d_in[1];
    int B = in_sizes[1];                 // 4096

    char* ws = (char*)d_ws;
    size_t o = 0;
    unsigned char* Fb16 = (unsigned char*)(ws + o); o += (size_t)BMAX * RB0;  // 1 MB
    float* sq = (float*)(ws + o);      o += (size_t)BMAX * 4;
    float* rb = (float*)(ws + o);      o += (size_t)BMAX * 4;
    int* perm = (int*)(ws + o);        o += (size_t)BMAX * 4;
    int* dom_off = (int*)(ws + o);     o += 64;
    int* ovf_cnt = (int*)(ws + o);     o += 64;
    int4* ovf = (int4*)(ws + o);       o += (size_t)OVF_CAP * 16;

    int nconv = (B + 3) >> 2;
    k_prep<<<nconv + 1, 256, 0, stream>>>(F, labels, B, Fb16, sq, rb, perm,
                                          dom_off, ovf_cnt);
    k_gram<<<GGRID, 256, 0, stream>>>(Fb16, sq, rb, perm, dom_off, ovf_cnt, ovf);
    k_final<<<1, 256, 0, stream>>>(F, sq, dom_off, ovf_cnt, ovf, (float*)d_out);
}